// Round 1
// baseline (5222.442 us; speedup 1.0000x reference)
//
#include <hip/hip_runtime.h>
#include <cstdint>

// VectorQuantizer on MI355X — round 1: exact fp32, fused distance+argmin.
//
// Numerics contract (must match numpy/jax fp32 reference argmin incl. ties):
//   d[n,k] = fl( sz[n] - 2*c[n,k] ),  c = fp32 FMA dot(z_n, W_k)
//   (the ||e_k||^2 term rounds away vs sz~256: 3e-7 < half-ulp(256)=1.5e-5)
//   argmin with FIRST-index tie-break == u64 atomicMin over (bits(d)<<32)|k
//   (d > 0 always, so positive-float bit pattern is order-monotone).
//
// Outputs in d_out (fp32 flat): z_q [16,256,32,32] (4194304) | loss (1) | idx (16384 as floats)

using u64 = unsigned long long;

#define NVEC   16384   // B*H*W query vectors
#define NEMB   16384   // codebook entries
#define DEPTH  256     // embed dim
#define ZQ_OFF 4194304
#define LOSS_OFF 4194304
#define IDX_OFF  4194305

__global__ __launch_bounds__(256) void k_init(u64* __restrict__ best, float* __restrict__ lossacc) {
    int i = blockIdx.x * 256 + threadIdx.x;
    if (i < NVEC) best[i] = ~0ull;
    if (i == 0) lossacc[0] = 0.0f;
}

// W [16384][256] -> Wt [256][16384]  (64x64 LDS tiles, +1 pad, both sides coalesced)
__global__ __launch_bounds__(256) void k_transpose_w(const float* __restrict__ W, float* __restrict__ Wt) {
    __shared__ float tile[64][65];
    int k0 = blockIdx.x * 64;
    int d0 = blockIdx.y * 64;
    int t = threadIdx.x, lane = t & 63, grp = t >> 6;
    for (int kk = grp; kk < 64; kk += 4)
        tile[kk][lane] = W[(k0 + kk) * DEPTH + d0 + lane];
    __syncthreads();
    for (int dd = grp; dd < 64; dd += 4)
        Wt[(d0 + dd) * NEMB + k0 + lane] = tile[lane][dd];
}

// sz[n] = fp32 sum of squares of z-row n. z is [16][256][1024]; row n=(b,hw) is strided 1024.
__global__ __launch_bounds__(256) void k_rownorm(const float* __restrict__ z, float* __restrict__ sz) {
    __shared__ float red[4][64];
    int bid = blockIdx.x;                  // 256 blocks: (b, hw-tile of 64)
    int b = bid >> 4, hw0 = (bid & 15) << 6;
    int t = threadIdx.x, r = t & 63, cg = t >> 6;
    const float* zp = z + b * 262144 + hw0 + r;
    float acc = 0.0f;
    for (int c = cg; c < DEPTH; c += 4) {
        float v = zp[c * 1024];
        acc = fmaf(v, v, acc);
    }
    red[cg][r] = acc;
    __syncthreads();
    if (t < 64)
        sz[bid * 64 + t] = (red[0][t] + red[1][t]) + (red[2][t] + red[3][t]);
}

// Main: 64(rows) x 64(codes) tile per block; each block loops 16 k-tiles (1024 codes),
// full depth 256 in 4 chunks of 64. 4x4 micro-tile per thread (16x16 threads).
__global__ __launch_bounds__(256) void k_main(const float* __restrict__ z,
                                              const float* __restrict__ Wt,
                                              const float* __restrict__ sz,
                                              u64* __restrict__ best) {
    __shared__ float As[64][64];   // [d][m]  (m = query rows: contiguous hw, matches z layout)
    __shared__ float Bs[64][64];   // [d][k]
    int ksup = blockIdx.x;         // 0..15  (k superblock of 1024 codes)
    int mt   = blockIdx.y;         // 0..255 (m tile of 64 rows)
    int b = mt >> 4, hw0 = (mt & 15) << 6;
    int m0 = mt << 6;
    int t = threadIdx.x;
    int lane = t & 63, grp = t >> 6;
    int tx = t & 15,  ty = t >> 4;
    int mloc = tx << 2, kloc = ty << 2;
    const float* zb = z + b * 262144 + hw0;

    float szr[4];
    u64 bk[4];
#pragma unroll
    for (int i = 0; i < 4; ++i) { szr[i] = sz[m0 + mloc + i]; bk[i] = ~0ull; }

    for (int kt = 0; kt < 16; ++kt) {
        int k0 = (ksup * 16 + kt) << 6;
        float acc[4][4];
#pragma unroll
        for (int i = 0; i < 4; ++i)
#pragma unroll
            for (int j = 0; j < 4; ++j) acc[i][j] = 0.0f;

        for (int dc = 0; dc < 4; ++dc) {
            int d0 = dc << 6;
            __syncthreads();
            // stage A (from z directly: A[d][m] == z[b][d][hw0+m], coalesced, 2-way LDS ~free)
            // stage B (from pre-transposed Wt: coalesced, conflict-free)
#pragma unroll
            for (int dd = grp; dd < 64; dd += 4) {
                As[dd][lane] = zb[(d0 + dd) * 1024 + lane];
                Bs[dd][lane] = Wt[(d0 + dd) * NEMB + k0 + lane];
            }
            __syncthreads();
#pragma unroll 8
            for (int dd = 0; dd < 64; ++dd) {
                const float4 a4 = *reinterpret_cast<const float4*>(&As[dd][mloc]);
                const float4 b4 = *reinterpret_cast<const float4*>(&Bs[dd][kloc]);
                float av[4] = {a4.x, a4.y, a4.z, a4.w};
                float bv[4] = {b4.x, b4.y, b4.z, b4.w};
#pragma unroll
                for (int i = 0; i < 4; ++i)
#pragma unroll
                    for (int j = 0; j < 4; ++j)
                        acc[i][j] = fmaf(av[i], bv[j], acc[i][j]);
            }
        }
        // fold this k-tile into running per-row best (exact rounding: fl(sz - 2c))
#pragma unroll
        for (int i = 0; i < 4; ++i) {
#pragma unroll
            for (int j = 0; j < 4; ++j) {
                float dv = szr[i] - 2.0f * acc[i][j];
                u64 key = ((u64)__float_as_uint(dv) << 32) | (unsigned)(k0 + kloc + j);
                bk[i] = (bk[i] < key) ? bk[i] : key;
            }
        }
    }

    // block-level per-row min over the 16 ty groups, then device atomicMin
    __syncthreads();
    u64* red = reinterpret_cast<u64*>(&As[0][0]);   // 64 rows x 16 groups = 8 KB
#pragma unroll
    for (int i = 0; i < 4; ++i) red[(mloc + i) * 16 + ty] = bk[i];
    __syncthreads();
    if (t < 64) {
        u64 m = red[t * 16];
#pragma unroll
        for (int j = 1; j < 16; ++j) { u64 v = red[t * 16 + j]; m = (m < v) ? m : v; }
        atomicMin(&best[m0 + t], m);
    }
}

// Gather W[idx] -> z_q in original [B,C,H,W] layout (coalesced along hw), idx as floats, loss partials.
__global__ __launch_bounds__(256) void k_epilogue(const float* __restrict__ z,
                                                  const float* __restrict__ Wc,
                                                  const u64* __restrict__ best,
                                                  float* __restrict__ out,
                                                  float* __restrict__ lossacc) {
    __shared__ unsigned kk[64];
    __shared__ float red[256];
    int bid = blockIdx.x;                  // 256 blocks: (b, hw-tile of 64)
    int b = bid >> 4, hw0 = (bid & 15) << 6;
    int n0 = bid << 6;
    int t = threadIdx.x, r = t & 63, cg = t >> 6;
    if (t < 64) {
        unsigned ki = (unsigned)(best[n0 + t] & 0xffffffffull);
        kk[t] = ki;
        out[IDX_OFF + n0 + t] = (float)ki;
    }
    __syncthreads();
    const float* wrow = Wc + (size_t)kk[r] * DEPTH;
    int zbase = b * 262144 + hw0 + r;
    float part = 0.0f;
    for (int c = cg; c < DEPTH; c += 4) {
        float w  = wrow[c];
        float zv = z[zbase + c * 1024];
        out[zbase + c * 1024] = w;
        float df = w - zv;
        part = fmaf(df, df, part);
    }
    red[t] = part;
    __syncthreads();
    for (int s = 128; s > 0; s >>= 1) {
        if (t < s) red[t] += red[t + s];
        __syncthreads();
    }
    if (t == 0) atomicAdd(lossacc, red[0]);
}

__global__ void k_loss_final(const float* __restrict__ lossacc, float* __restrict__ out) {
    // loss = (beta + 1) * mean(diff^2) = 1.25 * sum / 4194304
    out[LOSS_OFF] = lossacc[0] * (1.25f / 4194304.0f);
}

extern "C" void kernel_launch(void* const* d_in, const int* in_sizes, int n_in,
                              void* d_out, int out_size, void* d_ws, size_t ws_size,
                              hipStream_t stream) {
    const float* z = (const float*)d_in[0];
    const float* W = (const float*)d_in[1];
    float* out = (float*)d_out;
    char* ws = (char*)d_ws;

    float* Wt      = (float*)ws;                       // 256*16384*4 = 16,777,216 B
    float* sz      = (float*)(ws + 16777216);          // 65,536 B
    u64*   best    = (u64*)  (ws + 16842752);          // 131,072 B
    float* lossacc = (float*)(ws + 16973824);          // 4 B

    hipLaunchKernelGGL(k_init,        dim3(64),       dim3(256), 0, stream, best, lossacc);
    hipLaunchKernelGGL(k_transpose_w, dim3(256, 4),   dim3(256), 0, stream, W, Wt);
    hipLaunchKernelGGL(k_rownorm,     dim3(256),      dim3(256), 0, stream, z, sz);
    hipLaunchKernelGGL(k_main,        dim3(16, 256),  dim3(256), 0, stream, z, Wt, sz, best);
    hipLaunchKernelGGL(k_epilogue,    dim3(256),      dim3(256), 0, stream, z, W, best, out, lossacc);
    hipLaunchKernelGGL(k_loss_final,  dim3(1),        dim3(1),   0, stream, lossacc, out);
}

// Round 2
// 814.985 us; speedup vs baseline: 6.4080x; 6.4080x over previous
//
#include <hip/hip_runtime.h>
#include <cstdint>

// VectorQuantizer on MI355X — round 2: bf16-MFMA candidate filter + exact fp32 refine.
//
// Exactness: final winner computed by fp32 sequential-order dot identical to round-1's
// (which matched numpy). MFMA phase only *selects* candidates with a certified error
// bound: |d_approx - d_exact| <= Delta_n = 2^-7 * ||z_n|| * max_k||W_k|| (+slack).
//
// d_out (fp32 flat): z_q [16,256,32,32] (4194304) | loss (1) | idx (16384 as floats)
// z_q region of d_out doubles as scratch (tileMin/cand/cnt/tau) before the epilogue
// overwrites it — keeps ws usage within round-1's proven 16.97 MB footprint.

using u64 = unsigned long long;
using u32 = unsigned int;

#define NVEC   16384
#define NEMB   16384
#define DEPTH  256
#define LOSS_OFF 4194304
#define IDX_OFF  4194305

typedef __bf16 bf16x8 __attribute__((ext_vector_type(8)));
typedef float  f32x4  __attribute__((ext_vector_type(4)));

__device__ __forceinline__ void gld16(const void* g, void* l) {
    __builtin_amdgcn_global_load_lds(
        (const __attribute__((address_space(1))) char*)g,
        (__attribute__((address_space(3))) char*)l, 16, 0, 0);
}

__global__ __launch_bounds__(256) void k_init(u64* __restrict__ best, u32* __restrict__ wmax2) {
    int i = blockIdx.x * 256 + threadIdx.x;
    if (i < NVEC) best[i] = ~0ull;
    if (i == 0) *wmax2 = 0u;
}

// W [16384][256] f32 -> Wh bf16 (RNE); global max row-norm^2 via atomicMax on float bits.
__global__ __launch_bounds__(256) void k_prep_w(const float* __restrict__ W,
                                                __bf16* __restrict__ Wh,
                                                u32* __restrict__ wmax2) {
    int t = threadIdx.x, w = t >> 6, lane = t & 63;
    int row = blockIdx.x * 4 + w;
    const float4 v = *reinterpret_cast<const float4*>(W + (size_t)row * DEPTH + lane * 4);
    __bf16 h0 = (__bf16)v.x, h1 = (__bf16)v.y, h2 = (__bf16)v.z, h3 = (__bf16)v.w;
    ushort4 pk;
    pk.x = __builtin_bit_cast(unsigned short, h0);
    pk.y = __builtin_bit_cast(unsigned short, h1);
    pk.z = __builtin_bit_cast(unsigned short, h2);
    pk.w = __builtin_bit_cast(unsigned short, h3);
    *reinterpret_cast<ushort4*>(Wh + (size_t)row * DEPTH + lane * 4) = pk;
    float n2 = v.x * v.x + v.y * v.y + v.z * v.z + v.w * v.w;
#pragma unroll
    for (int s = 32; s > 0; s >>= 1) n2 += __shfl_down(n2, s, 64);
    if (lane == 0) atomicMax(wmax2, __float_as_uint(n2));
}

// z [16][256][1024] f32 -> Zh [n=16384][c=256] bf16 (transpose + convert)
__global__ __launch_bounds__(256) void k_prep_z(const float* __restrict__ z, __bf16* __restrict__ Zh) {
    __shared__ float tile[64][65];
    int hw0 = blockIdx.x * 64, c0 = blockIdx.y * 64, b = blockIdx.z;
    int t = threadIdx.x, lane = t & 63, grp = t >> 6;
    const float* zb = z + (size_t)b * 262144;
    for (int cc = grp; cc < 64; cc += 4)
        tile[cc][lane] = zb[(size_t)(c0 + cc) * 1024 + hw0 + lane];
    __syncthreads();
    for (int hh = grp; hh < 64; hh += 4)
        Zh[(size_t)(b * 1024 + hw0 + hh) * DEPTH + c0 + lane] = (__bf16)tile[lane][hh];
}

// sz[n] — EXACT copy of round-1 computation (feeds the exact d rounding).
__global__ __launch_bounds__(256) void k_rownorm(const float* __restrict__ z, float* __restrict__ sz) {
    __shared__ float red[4][64];
    int bid = blockIdx.x;
    int b = bid >> 4, hw0 = (bid & 15) << 6;
    int t = threadIdx.x, r = t & 63, cg = t >> 6;
    const float* zp = z + b * 262144 + hw0 + r;
    float acc = 0.0f;
    for (int c = cg; c < DEPTH; c += 4) {
        float v = zp[c * 1024];
        acc = fmaf(v, v, acc);
    }
    red[cg][r] = acc;
    __syncthreads();
    if (t < 64)
        sz[bid * 64 + t] = (red[0][t] + red[1][t]) + (red[2][t] + red[3][t]);
}

// bf16 MFMA GEMM: C-tile 128x128, BK=64, 4 waves (each 64x64 = 4x4 frags of 16x16x32).
// PASS 0: per-(row, ktile) min of d~ -> tileMinF.  PASS 1: d~ <= tau[n] -> append candidate.
template <int PASS>
__global__ __launch_bounds__(256) void k_gemm(const __bf16* __restrict__ Zh,
                                              const __bf16* __restrict__ Wh,
                                              const float* __restrict__ sz,
                                              const float* __restrict__ tau,
                                              float* __restrict__ tileMinF,
                                              u32* __restrict__ cand,
                                              u32* __restrict__ cnt) {
    __shared__ __bf16 As[128 * 64];
    __shared__ __bf16 Bs[128 * 64];
    __shared__ float red[128 * 2];
    const int kt = blockIdx.x, mt = blockIdx.y;
    const int m0 = mt * 128, k0 = kt * 128;
    const int t = threadIdx.x, w = t >> 6, lane = t & 63;
    const int quad = lane >> 4, l15 = lane & 15;
    const int wy = w >> 1, wx = w & 1;

    // staging: wave w loads rows {w*8 + (lane>>3)} + j*32; 16B per lane
    const int rowA = w * 8 + (lane >> 3);
    const int colb = (lane & 7) * 8;                      // bf16 elems within 64-wide chunk
    const __bf16* gA = Zh + (size_t)(m0 + rowA) * DEPTH + colb;
    const __bf16* gB = Wh + (size_t)(k0 + rowA) * DEPTH + colb;
    __bf16* lA = As + w * 8 * 64;
    __bf16* lB = Bs + w * 8 * 64;

    f32x4 acc[4][4] = {};
    float szr[4][4];
#pragma unroll
    for (int fi = 0; fi < 4; ++fi)
#pragma unroll
        for (int r = 0; r < 4; ++r)
            szr[fi][r] = sz[m0 + wy * 64 + fi * 16 + quad * 4 + r];

    for (int kb = 0; kb < 4; ++kb) {
        __syncthreads();
#pragma unroll
        for (int j = 0; j < 4; ++j) {
            gld16(gA + kb * 64 + j * 32 * DEPTH, lA + j * 32 * 64);
            gld16(gB + kb * 64 + j * 32 * DEPTH, lB + j * 32 * 64);
        }
        __syncthreads();
#pragma unroll
        for (int ks = 0; ks < 2; ++ks) {
            bf16x8 a[4], b[4];
#pragma unroll
            for (int fi = 0; fi < 4; ++fi)
                a[fi] = *reinterpret_cast<const bf16x8*>(As + (wy * 64 + fi * 16 + l15) * 64 + ks * 32 + quad * 8);
#pragma unroll
            for (int fj = 0; fj < 4; ++fj)
                b[fj] = *reinterpret_cast<const bf16x8*>(Bs + (wx * 64 + fj * 16 + l15) * 64 + ks * 32 + quad * 8);
#pragma unroll
            for (int fi = 0; fi < 4; ++fi)
#pragma unroll
                for (int fj = 0; fj < 4; ++fj)
                    acc[fi][fj] = __builtin_amdgcn_mfma_f32_16x16x32_bf16(a[fi], b[fj], acc[fi][fj], 0, 0, 0);
        }
    }

    if (PASS == 0) {
#pragma unroll
        for (int fi = 0; fi < 4; ++fi)
#pragma unroll
            for (int r = 0; r < 4; ++r) {
                float v = szr[fi][r] - 2.0f * acc[fi][0][r];
#pragma unroll
                for (int fj = 1; fj < 4; ++fj)
                    v = fminf(v, szr[fi][r] - 2.0f * acc[fi][fj][r]);
                v = fminf(v, __shfl_xor(v, 1, 64));
                v = fminf(v, __shfl_xor(v, 2, 64));
                v = fminf(v, __shfl_xor(v, 4, 64));
                v = fminf(v, __shfl_xor(v, 8, 64));
                if (l15 == 0) red[(wy * 64 + fi * 16 + quad * 4 + r) * 2 + wx] = v;
            }
        __syncthreads();
        if (t < 128)
            tileMinF[(size_t)(m0 + t) * 128 + kt] = fminf(red[t * 2], red[t * 2 + 1]);
    } else {
#pragma unroll
        for (int fi = 0; fi < 4; ++fi)
#pragma unroll
            for (int r = 0; r < 4; ++r) {
                int n = m0 + wy * 64 + fi * 16 + quad * 4 + r;
                float ta = tau[n];
#pragma unroll
                for (int fj = 0; fj < 4; ++fj) {
                    float dv = szr[fi][r] - 2.0f * acc[fi][fj][r];
                    if (dv <= ta) {
                        u32 kg = (u32)(k0 + wx * 64 + fj * 16 + l15);
                        u32 p = atomicAdd(&cnt[n], 1u);
                        if (p < 32u) cand[n * 32 + p] = kg;
                    }
                }
            }
    }
}

// per-row min over 128 tile-mins -> tau[n] = gmin + 2*Delta_n ; zero cnt; zero lossacc.
__global__ __launch_bounds__(256) void k_rowmin(const float* __restrict__ tileMinF,
                                                const float* __restrict__ sz,
                                                const u32* __restrict__ wmax2,
                                                float* __restrict__ tau,
                                                u32* __restrict__ cnt,
                                                float* __restrict__ lossacc) {
    int t = threadIdx.x, w = t >> 6, lane = t & 63;
    int row = blockIdx.x * 4 + w;
    float v = fminf(tileMinF[(size_t)row * 128 + lane], tileMinF[(size_t)row * 128 + 64 + lane]);
#pragma unroll
    for (int m = 1; m < 64; m <<= 1) v = fminf(v, __shfl_xor(v, m, 64));
    if (lane == 0) {
        float wm = sqrtf(__uint_as_float(*wmax2));
        float delta = 0.009f * sqrtf(sz[row]) * wm + 1.0e-4f;
        tau[row] = v + 2.0f * delta;
        cnt[row] = 0u;
        if (row == 0) *lossacc = 0.0f;
    }
}

// exact fp32 refine: per row, sequential-order dot (bit-identical to round-1) over candidates.
__global__ __launch_bounds__(256) void k_refine(const float* __restrict__ z,
                                                const float* __restrict__ W,
                                                const float* __restrict__ sz,
                                                const u32* __restrict__ cand,
                                                const u32* __restrict__ cnt,
                                                u64* __restrict__ best) {
    __shared__ float zrow[4][256];
    int t = threadIdx.x, w = t >> 6, lane = t & 63;
    int row = blockIdx.x * 4 + w;
    int b = row >> 10, hw = row & 1023;
    const float* zb = z + (size_t)b * 262144 + hw;
#pragma unroll
    for (int j = 0; j < 4; ++j)
        zrow[w][j * 64 + lane] = zb[(size_t)(j * 64 + lane) * 1024];
    __syncthreads();
    float szv = sz[row];
    u32 cn = cnt[row];
    u64 mykey = ~0ull;
    if (cn >= 1u && cn <= 32u) {
        if (lane < (int)cn) {
            u32 kg = cand[row * 32 + lane];
            const float* wr = W + (size_t)kg * DEPTH;
            float a = 0.0f;
#pragma unroll 8
            for (int c = 0; c < DEPTH; ++c) a = fmaf(zrow[w][c], wr[c], a);
            float dv = szv - 2.0f * a;
            mykey = ((u64)__float_as_uint(dv) << 32) | kg;
        }
    } else {
        // pathological fallback (cnt==0 impossible by construction; cnt>32 ~never): full scan
        for (int kg = lane; kg < NEMB; kg += 64) {
            const float* wr = W + (size_t)kg * DEPTH;
            float a = 0.0f;
#pragma unroll 8
            for (int c = 0; c < DEPTH; ++c) a = fmaf(zrow[w][c], wr[c], a);
            float dv = szv - 2.0f * a;
            u64 key = ((u64)__float_as_uint(dv) << 32) | (u32)kg;
            mykey = (mykey < key) ? mykey : key;
        }
    }
#pragma unroll
    for (int m = 1; m < 64; m <<= 1) {
        u64 o = __shfl_xor(mykey, m, 64);
        mykey = (mykey < o) ? mykey : o;
    }
    if (lane == 0) best[row] = mykey;
}

// gather W[idx] -> z_q in [B,C,H,W] layout, idx as floats, loss partials (round-1 verbatim).
__global__ __launch_bounds__(256) void k_epilogue(const float* __restrict__ z,
                                                  const float* __restrict__ Wc,
                                                  const u64* __restrict__ best,
                                                  float* __restrict__ out,
                                                  float* __restrict__ lossacc) {
    __shared__ unsigned kk[64];
    __shared__ float red[256];
    int bid = blockIdx.x;
    int b = bid >> 4, hw0 = (bid & 15) << 6;
    int n0 = bid << 6;
    int t = threadIdx.x, r = t & 63, cg = t >> 6;
    if (t < 64) {
        unsigned ki = (unsigned)(best[n0 + t] & 0xffffffffull);
        kk[t] = ki;
        out[IDX_OFF + n0 + t] = (float)ki;
    }
    __syncthreads();
    const float* wrow = Wc + (size_t)kk[r] * DEPTH;
    int zbase = b * 262144 + hw0 + r;
    float part = 0.0f;
    for (int c = cg; c < DEPTH; c += 4) {
        float wv = wrow[c];
        float zv = z[zbase + c * 1024];
        out[zbase + c * 1024] = wv;
        float df = wv - zv;
        part = fmaf(df, df, part);
    }
    red[t] = part;
    __syncthreads();
    for (int s = 128; s > 0; s >>= 1) {
        if (t < s) red[t] += red[t + s];
        __syncthreads();
    }
    if (t == 0) atomicAdd(lossacc, red[0]);
}

__global__ void k_loss_final(float* __restrict__ out) {
    out[LOSS_OFF] = out[LOSS_OFF] * (1.25f / 4194304.0f);
}

extern "C" void kernel_launch(void* const* d_in, const int* in_sizes, int n_in,
                              void* d_out, int out_size, void* d_ws, size_t ws_size,
                              hipStream_t stream) {
    const float* z = (const float*)d_in[0];
    const float* W = (const float*)d_in[1];
    float* out = (float*)d_out;
    char* ws = (char*)d_ws;

    // ws (16.97 MB, == round-1 proven footprint):
    __bf16* Zh   = (__bf16*)ws;                          // 8,388,608 B
    __bf16* Wh   = (__bf16*)(ws + 8388608);              // 8,388,608 B
    float*  sz   = (float*) (ws + 16777216);             // 65,536 B
    u64*    best = (u64*)   (ws + 16842752);             // 131,072 B -> end 16,973,824

    // scratch inside d_out's z_q region (fully overwritten by k_epilogue afterwards):
    float* tileMinF = out;                               // 16384*128 f32 = 8 MB
    u32*   cand     = (u32*)(out + 2097152);             // 16384*32 u32 = 2 MB
    u32*   cnt      = (u32*)(out + 2621440);             // 16384 u32
    float* tau      = out + 2637824;                     // 16384 f32
    u32*   wmax2    = (u32*)(out + 2654208);             // 1 u32
    float* lossacc  = out + LOSS_OFF;                    // the loss slot itself

    k_init      <<<dim3(64),        dim3(256), 0, stream>>>(best, wmax2);
    k_prep_w    <<<dim3(4096),      dim3(256), 0, stream>>>(W, Wh, wmax2);
    k_prep_z    <<<dim3(16, 4, 16), dim3(256), 0, stream>>>(z, Zh);
    k_rownorm   <<<dim3(256),       dim3(256), 0, stream>>>(z, sz);
    k_gemm<0>   <<<dim3(128, 128),  dim3(256), 0, stream>>>(Zh, Wh, sz, tau, tileMinF, cand, cnt);
    k_rowmin    <<<dim3(4096),      dim3(256), 0, stream>>>(tileMinF, sz, wmax2, tau, cnt, lossacc);
    k_gemm<1>   <<<dim3(128, 128),  dim3(256), 0, stream>>>(Zh, Wh, sz, tau, tileMinF, cand, cnt);
    k_refine    <<<dim3(4096),      dim3(256), 0, stream>>>(z, W, sz, cand, cnt, best);
    k_epilogue  <<<dim3(256),       dim3(256), 0, stream>>>(z, W, best, out, lossacc);
    k_loss_final<<<dim3(1),         dim3(1),   0, stream>>>(out);
}

// Round 3
// 755.823 us; speedup vs baseline: 6.9096x; 1.0783x over previous
//
#include <hip/hip_runtime.h>
#include <cstdint>

// VectorQuantizer on MI355X — round 3: single-pass bf16-MFMA (two-min+argmin epilogue),
// XOR-swizzled LDS (kills the 16-way ds_read_b128 conflicts), exact fp32 refine with
// ballot-driven rare tile rescans. Exact-argmin coverage proof in round-2/3 notes.
//
// d_out (fp32 flat): z_q [16,256,32,32] (4194304) | loss (1) | idx (16384 as floats)
// tilePack (u64 per row x 128 tiles = exactly 16 MB) lives in d_out's z_q region,
// fully overwritten by the epilogue afterwards.

using u64 = unsigned long long;
using u32 = unsigned int;

#define NVEC   16384
#define NEMB   16384
#define DEPTH  256
#define LOSS_OFF 4194304
#define IDX_OFF  4194305

typedef __bf16 bf16x8 __attribute__((ext_vector_type(8)));
typedef float  f32x4  __attribute__((ext_vector_type(4)));

__device__ __forceinline__ void gld16(const void* g, void* l) {
    __builtin_amdgcn_global_load_lds(
        (const __attribute__((address_space(1))) char*)g,
        (__attribute__((address_space(3))) char*)l, 16, 0, 0);
}
__device__ __forceinline__ u64 umin64(u64 a, u64 b) { return a < b ? a : b; }

__global__ void k_init(u32* __restrict__ wmax2, float* __restrict__ out) {
    if (threadIdx.x == 0) { *wmax2 = 0u; out[LOSS_OFF] = 0.0f; }
}

// W [16384][256] f32 -> Wh bf16 (RNE); global max row-norm^2 via atomicMax on float bits.
__global__ __launch_bounds__(256) void k_prep_w(const float* __restrict__ W,
                                                __bf16* __restrict__ Wh,
                                                u32* __restrict__ wmax2) {
    int t = threadIdx.x, w = t >> 6, lane = t & 63;
    int row = blockIdx.x * 4 + w;
    const float4 v = *reinterpret_cast<const float4*>(W + (size_t)row * DEPTH + lane * 4);
    __bf16 h0 = (__bf16)v.x, h1 = (__bf16)v.y, h2 = (__bf16)v.z, h3 = (__bf16)v.w;
    ushort4 pk;
    pk.x = __builtin_bit_cast(unsigned short, h0);
    pk.y = __builtin_bit_cast(unsigned short, h1);
    pk.z = __builtin_bit_cast(unsigned short, h2);
    pk.w = __builtin_bit_cast(unsigned short, h3);
    *reinterpret_cast<ushort4*>(Wh + (size_t)row * DEPTH + lane * 4) = pk;
    float n2 = v.x * v.x + v.y * v.y + v.z * v.z + v.w * v.w;
#pragma unroll
    for (int s = 32; s > 0; s >>= 1) n2 += __shfl_down(n2, s, 64);
    if (lane == 0) atomicMax(wmax2, __float_as_uint(n2));
}

// z [16][256][1024] f32 -> Zh [n=16384][c=256] bf16 (transpose + convert)
__global__ __launch_bounds__(256) void k_prep_z(const float* __restrict__ z, __bf16* __restrict__ Zh) {
    __shared__ float tile[64][65];
    int hw0 = blockIdx.x * 64, c0 = blockIdx.y * 64, b = blockIdx.z;
    int t = threadIdx.x, lane = t & 63, grp = t >> 6;
    const float* zb = z + (size_t)b * 262144;
    for (int cc = grp; cc < 64; cc += 4)
        tile[cc][lane] = zb[(size_t)(c0 + cc) * 1024 + hw0 + lane];
    __syncthreads();
    for (int hh = grp; hh < 64; hh += 4)
        Zh[(size_t)(b * 1024 + hw0 + hh) * DEPTH + c0 + lane] = (__bf16)tile[lane][hh];
}

// sz[n] — EXACT copy of round-1 computation (exactness anchor; do not change).
__global__ __launch_bounds__(256) void k_rownorm(const float* __restrict__ z, float* __restrict__ sz) {
    __shared__ float red[4][64];
    int bid = blockIdx.x;
    int b = bid >> 4, hw0 = (bid & 15) << 6;
    int t = threadIdx.x, r = t & 63, cg = t >> 6;
    const float* zp = z + b * 262144 + hw0 + r;
    float acc = 0.0f;
    for (int c = cg; c < DEPTH; c += 4) {
        float v = zp[c * 1024];
        acc = fmaf(v, v, acc);
    }
    red[cg][r] = acc;
    __syncthreads();
    if (t < 64)
        sz[bid * 64 + t] = (red[0][t] + red[1][t]) + (red[2][t] + red[3][t]);
}

// Single-pass MFMA GEMM, C-tile 128x128, BK=64. LDS chunk-XOR swizzle (chunk^=(row&7)),
// applied on the global-source side of global_load_lds. Epilogue: per (row, tile)
// two-min (m1,m2), argmin k1 (match-scan), flag = (m2 <= m1 + 2E) -> packed u64.
__global__ __launch_bounds__(256) void k_gemm(const __bf16* __restrict__ Zh,
                                              const __bf16* __restrict__ Wh,
                                              const float* __restrict__ sz,
                                              const u32* __restrict__ wmax2,
                                              u64* __restrict__ tilePack) {
    __shared__ __bf16 As[128 * 64];
    __shared__ __bf16 Bs[128 * 64];
    __shared__ float m1red[128 * 2];
    __shared__ float m2red[128 * 2];
    __shared__ u32   k1red[128 * 2];
    const int kt = blockIdx.x, mt = blockIdx.y;
    const int m0 = mt * 128, k0 = kt * 128;
    const int t = threadIdx.x, w = t >> 6, lane = t & 63;
    const int quad = lane >> 4, l15 = lane & 15;
    const int wy = w >> 1, wx = w & 1;

    // staging: wave w covers rows {w*8 + lane>>3} (+j*32); XOR-swizzled source column.
    const int rowA = w * 8 + (lane >> 3);
    const int colb = (((lane & 7) ^ (lane >> 3)) * 8);     // bf16 elems, swizzled chunk
    const __bf16* gA = Zh + (size_t)(m0 + rowA) * DEPTH + colb;
    const __bf16* gB = Wh + (size_t)(k0 + rowA) * DEPTH + colb;
    __bf16* lA = As + w * 8 * 64;
    __bf16* lB = Bs + w * 8 * 64;

    f32x4 acc[4][4] = {};
    float szr[4][4];
#pragma unroll
    for (int fi = 0; fi < 4; ++fi)
#pragma unroll
        for (int r = 0; r < 4; ++r)
            szr[fi][r] = sz[m0 + wy * 64 + fi * 16 + quad * 4 + r];

    for (int kb = 0; kb < 4; ++kb) {
        __syncthreads();
#pragma unroll
        for (int j = 0; j < 4; ++j) {
            gld16(gA + kb * 64 + j * 32 * DEPTH, lA + j * 32 * 64);
            gld16(gB + kb * 64 + j * 32 * DEPTH, lB + j * 32 * 64);
        }
        __syncthreads();
#pragma unroll
        for (int ks = 0; ks < 2; ++ks) {
            const int ph = ((ks * 4 + quad) ^ (l15 & 7)) * 8;   // swizzled chunk -> bf16 offset
            bf16x8 a[4], b[4];
#pragma unroll
            for (int fi = 0; fi < 4; ++fi)
                a[fi] = *reinterpret_cast<const bf16x8*>(As + (wy * 64 + fi * 16 + l15) * 64 + ph);
#pragma unroll
            for (int fj = 0; fj < 4; ++fj)
                b[fj] = *reinterpret_cast<const bf16x8*>(Bs + (wx * 64 + fj * 16 + l15) * 64 + ph);
#pragma unroll
            for (int fi = 0; fi < 4; ++fi)
#pragma unroll
                for (int fj = 0; fj < 4; ++fj)
                    acc[fi][fj] = __builtin_amdgcn_mfma_f32_16x16x32_bf16(a[fi], b[fj], acc[fi][fj], 0, 0, 0);
        }
    }

    // ---- epilogue: per-row two-min + argmin over this 128-wide tile ----
#pragma unroll
    for (int fi = 0; fi < 4; ++fi) {
#pragma unroll
        for (int r = 0; r < 4; ++r) {
            float x0 = fmaf(-2.0f, acc[fi][0][r], szr[fi][r]);
            float x1 = fmaf(-2.0f, acc[fi][1][r], szr[fi][r]);
            float x2 = fmaf(-2.0f, acc[fi][2][r], szr[fi][r]);
            float x3 = fmaf(-2.0f, acc[fi][3][r], szr[fi][r]);
            float lo01 = fminf(x0, x1), hi01 = fmaxf(x0, x1);
            float lo23 = fminf(x2, x3), hi23 = fmaxf(x2, x3);
            float m1 = fminf(lo01, lo23);
            float m2 = fminf(fmaxf(lo01, lo23), fminf(hi01, hi23));
            // multiset two-min tree reduction over the 16 l15 lanes
#pragma unroll
            for (int mm = 1; mm < 16; mm <<= 1) {
                float o1 = __shfl_xor(m1, mm, 64);
                float o2 = __shfl_xor(m2, mm, 64);
                m2 = fminf(fminf(m2, o2), fmaxf(m1, o1));
                m1 = fminf(m1, o1);
            }
            // match-scan for first-index argmin (k local to this 64-wide half: fj*16+l15)
            u32 kl = 0xFFFFu;
            kl = (x3 == m1) ? (u32)(48 + l15) : kl;
            kl = (x2 == m1) ? (u32)(32 + l15) : kl;
            kl = (x1 == m1) ? (u32)(16 + l15) : kl;
            kl = (x0 == m1) ? (u32)(l15)      : kl;
#pragma unroll
            for (int mm = 1; mm < 16; mm <<= 1) {
                u32 ok = __shfl_xor(kl, mm, 64);
                kl = kl < ok ? kl : ok;
            }
            if (l15 == 0) {
                int rowl = wy * 64 + fi * 16 + quad * 4 + r;
                m1red[rowl * 2 + wx] = m1;
                m2red[rowl * 2 + wx] = m2;
                k1red[rowl * 2 + wx] = kl;
            }
        }
    }
    __syncthreads();
    if (t < 128) {
        int n = m0 + t;
        float m1a = m1red[t * 2], m1b = m1red[t * 2 + 1];
        float m2a = m2red[t * 2], m2b = m2red[t * 2 + 1];
        u32 ka = k1red[t * 2], kb = k1red[t * 2 + 1] + 64;
        bool bl = m1b < m1a;                 // tie -> a (smaller k) wins
        float m1 = bl ? m1b : m1a;
        u32 k1 = bl ? kb : ka;
        float m2 = fminf(fminf(m2a, m2b), fmaxf(m1a, m1b));
        float E = 0.008f * sqrtf(sz[n]) * sqrtf(__uint_as_float(*wmax2)) + 5.0e-5f;
        u32 flag = (m2 <= m1 + 2.0f * E) ? 0x80000000u : 0u;
        tilePack[(size_t)n * 128 + kt] = ((u64)__float_as_uint(m1) << 32) | (u64)(k1 | flag);
    }
}

// exact fp32 refine: per row compute tau = gmin + 2E from tilePack, dot k1 candidates
// (reference-order sequential fmaf), ballot-rescan flagged tiles, write best (no atomics).
__global__ __launch_bounds__(256) void k_refine(const float* __restrict__ z,
                                                const float* __restrict__ W,
                                                const float* __restrict__ sz,
                                                const u32* __restrict__ wmax2,
                                                const u64* __restrict__ tp,
                                                u64* __restrict__ best) {
    __shared__ float zt[32][264];            // stride 264: 16B-aligned rows, 2-way-free banks
    const int n0 = blockIdx.x * 32;
    const int b = n0 >> 10, hw0 = n0 & 1023;
    const int t = threadIdx.x;
    {
        int hw = t & 31, cg = t >> 5;
        const float* zb = z + (size_t)b * 262144 + hw0 + hw;
        for (int i = 0; i < 32; ++i) {
            int c = i * 8 + cg;
            zt[hw][c] = zb[(size_t)c * 1024];
        }
    }
    __syncthreads();
    const float wmaxv = sqrtf(__uint_as_float(*wmax2));
    const int w = t >> 6, lane = t & 63;
    for (int rr = w; rr < 32; rr += 4) {
        const int n = n0 + rr;
        const u64* tpn = tp + (size_t)n * 128;
        u64 p0 = tpn[lane], p1 = tpn[lane + 64];
        float f0 = __uint_as_float((u32)(p0 >> 32));
        float f1 = __uint_as_float((u32)(p1 >> 32));
        float g = fminf(f0, f1);
#pragma unroll
        for (int mm = 1; mm < 64; mm <<= 1) g = fminf(g, __shfl_xor(g, mm, 64));
        const float szv = sz[n];
        const float E = 0.008f * sqrtf(szv) * wmaxv + 5.0e-5f;
        const float tau = g + 2.0f * E;
        const float4* zrow = reinterpret_cast<const float4*>(&zt[rr][0]);
        u64 mykey = ~0ull;
#pragma unroll
        for (int half = 0; half < 2; ++half) {
            const u64 p = half ? p1 : p0;
            const float m1 = half ? f1 : f0;
            const u32 low = (u32)p;
            const bool qual = (m1 <= tau);
            const bool fl = (low & 0x80000000u) != 0u;
            if (qual && !fl) {
                u32 kg = (u32)((lane + half * 64) * 128) + (low & 0x7FFFFFFFu);
                const float4* wr = reinterpret_cast<const float4*>(W + (size_t)kg * DEPTH);
                float a = 0.0f;
                for (int c = 0; c < 64; ++c) {
                    float4 wv = wr[c]; float4 zv = zrow[c];
                    a = fmaf(zv.x, wv.x, a); a = fmaf(zv.y, wv.y, a);
                    a = fmaf(zv.z, wv.z, a); a = fmaf(zv.w, wv.w, a);
                }
                float dv = szv - 2.0f * a;
                mykey = umin64(mykey, ((u64)__float_as_uint(dv) << 32) | kg);
            }
            u64 bal = __ballot(qual && fl);
            while (bal) {
                int lt = __builtin_ctzll(bal);
                bal &= bal - 1;
                int ktile = lt + half * 64;
#pragma unroll
                for (int s = 0; s < 2; ++s) {
                    u32 kg = (u32)(ktile * 128 + s * 64 + lane);
                    const float4* wr = reinterpret_cast<const float4*>(W + (size_t)kg * DEPTH);
                    float a = 0.0f;
                    for (int c = 0; c < 64; ++c) {
                        float4 wv = wr[c]; float4 zv = zrow[c];
                        a = fmaf(zv.x, wv.x, a); a = fmaf(zv.y, wv.y, a);
                        a = fmaf(zv.z, wv.z, a); a = fmaf(zv.w, wv.w, a);
                    }
                    float dv = szv - 2.0f * a;
                    mykey = umin64(mykey, ((u64)__float_as_uint(dv) << 32) | kg);
                }
            }
        }
#pragma unroll
        for (int mm = 1; mm < 64; mm <<= 1)
            mykey = umin64(mykey, __shfl_xor(mykey, mm, 64));
        if (lane == 0) best[n] = mykey;
    }
}

// gather W[idx] -> z_q in [B,C,H,W] layout, idx as floats, loss partials (round-1 verbatim).
__global__ __launch_bounds__(256) void k_epilogue(const float* __restrict__ z,
                                                  const float* __restrict__ Wc,
                                                  const u64* __restrict__ best,
                                                  float* __restrict__ out,
                                                  float* __restrict__ lossacc) {
    __shared__ unsigned kk[64];
    __shared__ float red[256];
    int bid = blockIdx.x;
    int b = bid >> 4, hw0 = (bid & 15) << 6;
    int n0 = bid << 6;
    int t = threadIdx.x, r = t & 63, cg = t >> 6;
    if (t < 64) {
        unsigned ki = (unsigned)(best[n0 + t] & 0xffffffffull);
        kk[t] = ki;
        out[IDX_OFF + n0 + t] = (float)ki;
    }
    __syncthreads();
    const float* wrow = Wc + (size_t)kk[r] * DEPTH;
    int zbase = b * 262144 + hw0 + r;
    float part = 0.0f;
    for (int c = cg; c < DEPTH; c += 4) {
        float wv = wrow[c];
        float zv = z[zbase + c * 1024];
        out[zbase + c * 1024] = wv;
        float df = wv - zv;
        part = fmaf(df, df, part);
    }
    red[t] = part;
    __syncthreads();
    for (int s = 128; s > 0; s >>= 1) {
        if (t < s) red[t] += red[t + s];
        __syncthreads();
    }
    if (t == 0) atomicAdd(lossacc, red[0]);
}

__global__ void k_loss_final(float* __restrict__ out) {
    out[LOSS_OFF] = out[LOSS_OFF] * (1.25f / 4194304.0f);
}

extern "C" void kernel_launch(void* const* d_in, const int* in_sizes, int n_in,
                              void* d_out, int out_size, void* d_ws, size_t ws_size,
                              hipStream_t stream) {
    const float* z = (const float*)d_in[0];
    const float* W = (const float*)d_in[1];
    float* out = (float*)d_out;
    char* ws = (char*)d_ws;

    // ws layout (within round-1's proven 16,973,828 B footprint):
    __bf16* Zh    = (__bf16*)ws;                         // 8,388,608 B
    __bf16* Wh    = (__bf16*)(ws + 8388608);             // 8,388,608 B
    float*  sz    = (float*) (ws + 16777216);            // 65,536 B
    u64*    best  = (u64*)   (ws + 16842752);            // 131,072 B
    u32*    wmax2 = (u32*)   (ws + 16973824);            // 4 B

    // tilePack: exactly the 16 MB z_q region of d_out (overwritten by epilogue later)
    u64* tilePack = (u64*)out;
    float* lossacc = out + LOSS_OFF;

    k_init      <<<dim3(1),         dim3(64),  0, stream>>>(wmax2, out);
    k_prep_w    <<<dim3(4096),      dim3(256), 0, stream>>>(W, Wh, wmax2);
    k_prep_z    <<<dim3(16, 4, 16), dim3(256), 0, stream>>>(z, Zh);
    k_rownorm   <<<dim3(256),       dim3(256), 0, stream>>>(z, sz);
    k_gemm      <<<dim3(128, 128),  dim3(256), 0, stream>>>(Zh, Wh, sz, wmax2, tilePack);
    k_refine    <<<dim3(512),       dim3(256), 0, stream>>>(z, W, sz, wmax2, tilePack, best);
    k_epilogue  <<<dim3(256),       dim3(256), 0, stream>>>(z, W, best, out, lossacc);
    k_loss_final<<<dim3(1),         dim3(1),   0, stream>>>(out);
}

// Round 4
// 572.901 us; speedup vs baseline: 9.1158x; 1.3193x over previous
//
#include <hip/hip_runtime.h>
#include <cstdint>

// VectorQuantizer on MI355X — round 4: orientation-swapped MFMA GEMM (codes = C-rows,
// queries = C-cols) so the per-query 128-code two-min/argmin lives in REGISTERS
// (round-3's 192 ds_bpermute/lane epilogue -> ~26), + coalesced kt-major tilePack.
// Filter math unchanged: certified bf16 bound E, exact fp32 refine (round-1 order).
//
// d_out (fp32 flat): z_q [16,256,32,32] (4194304) | loss (1) | idx (16384 as floats)
// tilePack (u64 x 128 x 16384 = 16 MB) lives in d_out's z_q region, overwritten later.

using u64 = unsigned long long;
using u32 = unsigned int;

#define NVEC   16384
#define NEMB   16384
#define DEPTH  256
#define LOSS_OFF 4194304
#define IDX_OFF  4194305

typedef __bf16 bf16x8 __attribute__((ext_vector_type(8)));
typedef float  f32x4  __attribute__((ext_vector_type(4)));

__device__ __forceinline__ void gld16(const void* g, void* l) {
    __builtin_amdgcn_global_load_lds(
        (const __attribute__((address_space(1))) char*)g,
        (__attribute__((address_space(3))) char*)l, 16, 0, 0);
}
__device__ __forceinline__ u64 umin64(u64 a, u64 b) { return a < b ? a : b; }
__device__ __forceinline__ u64 umax64(u64 a, u64 b) { return a > b ? a : b; }

__global__ void k_init(u32* __restrict__ wmax2, float* __restrict__ out) {
    if (threadIdx.x == 0) { *wmax2 = 0u; out[LOSS_OFF] = 0.0f; }
}

// W [16384][256] f32 -> Wh bf16 (RNE); global max row-norm^2 via atomicMax on float bits.
__global__ __launch_bounds__(256) void k_prep_w(const float* __restrict__ W,
                                                __bf16* __restrict__ Wh,
                                                u32* __restrict__ wmax2) {
    int t = threadIdx.x, w = t >> 6, lane = t & 63;
    int row = blockIdx.x * 4 + w;
    const float4 v = *reinterpret_cast<const float4*>(W + (size_t)row * DEPTH + lane * 4);
    __bf16 h0 = (__bf16)v.x, h1 = (__bf16)v.y, h2 = (__bf16)v.z, h3 = (__bf16)v.w;
    ushort4 pk;
    pk.x = __builtin_bit_cast(unsigned short, h0);
    pk.y = __builtin_bit_cast(unsigned short, h1);
    pk.z = __builtin_bit_cast(unsigned short, h2);
    pk.w = __builtin_bit_cast(unsigned short, h3);
    *reinterpret_cast<ushort4*>(Wh + (size_t)row * DEPTH + lane * 4) = pk;
    float n2 = v.x * v.x + v.y * v.y + v.z * v.z + v.w * v.w;
#pragma unroll
    for (int s = 32; s > 0; s >>= 1) n2 += __shfl_down(n2, s, 64);
    if (lane == 0) atomicMax(wmax2, __float_as_uint(n2));
}

// z [16][256][1024] f32 -> Zh [n=16384][c=256] bf16 (transpose + convert)
__global__ __launch_bounds__(256) void k_prep_z(const float* __restrict__ z, __bf16* __restrict__ Zh) {
    __shared__ float tile[64][65];
    int hw0 = blockIdx.x * 64, c0 = blockIdx.y * 64, b = blockIdx.z;
    int t = threadIdx.x, lane = t & 63, grp = t >> 6;
    const float* zb = z + (size_t)b * 262144;
    for (int cc = grp; cc < 64; cc += 4)
        tile[cc][lane] = zb[(size_t)(c0 + cc) * 1024 + hw0 + lane];
    __syncthreads();
    for (int hh = grp; hh < 64; hh += 4)
        Zh[(size_t)(b * 1024 + hw0 + hh) * DEPTH + c0 + lane] = (__bf16)tile[lane][hh];
}

// sz[n] — EXACT copy of round-1 computation (exactness anchor; do not change).
__global__ __launch_bounds__(256) void k_rownorm(const float* __restrict__ z, float* __restrict__ sz) {
    __shared__ float red[4][64];
    int bid = blockIdx.x;
    int b = bid >> 4, hw0 = (bid & 15) << 6;
    int t = threadIdx.x, r = t & 63, cg = t >> 6;
    const float* zp = z + b * 262144 + hw0 + r;
    float acc = 0.0f;
    for (int c = cg; c < DEPTH; c += 4) {
        float v = zp[c * 1024];
        acc = fmaf(v, v, acc);
    }
    red[cg][r] = acc;
    __syncthreads();
    if (t < 64)
        sz[bid * 64 + t] = (red[0][t] + red[1][t]) + (red[2][t] + red[3][t]);
}

// MFMA GEMM, C-tile = 128 codes (rows) x 128 queries (cols), BK=64, XOR-swizzled LDS.
// Register-side epilogue: per query, two-min+argmin over its 64 in-wave code values
// (16 regs x 4 quad-lanes), then 2-wave LDS combine -> packed u64 per (kt, n).
__global__ __launch_bounds__(256, 4) void k_gemm(const __bf16* __restrict__ Wh,
                                                 const __bf16* __restrict__ Zh,
                                                 const float* __restrict__ sz,
                                                 const u32* __restrict__ wmax2,
                                                 u64* __restrict__ tilePack) {
    __shared__ __bf16 As[128 * 64];          // codes
    __shared__ __bf16 Bs[128 * 64];          // queries
    __shared__ u64   keyred[128 * 2];
    __shared__ float m2red[128 * 2];
    const int kt = blockIdx.x, nt = blockIdx.y;
    const int k0 = kt * 128, n0 = nt * 128;
    const int t = threadIdx.x, w = t >> 6, lane = t & 63;
    const int quad = lane >> 4, l15 = lane & 15;
    const int wy = w >> 1, wx = w & 1;       // wy: code half, wx: query half

    const int rowS = w * 8 + (lane >> 3);
    const int colb = (((lane & 7) ^ (lane >> 3)) * 8);
    const __bf16* gA = Wh + (size_t)(k0 + rowS) * DEPTH + colb;
    const __bf16* gB = Zh + (size_t)(n0 + rowS) * DEPTH + colb;
    __bf16* lA = As + w * 8 * 64;
    __bf16* lB = Bs + w * 8 * 64;

    f32x4 acc[4][4] = {};
    float szq[4];
#pragma unroll
    for (int fj = 0; fj < 4; ++fj)
        szq[fj] = sz[n0 + wx * 64 + fj * 16 + l15];

    for (int kb = 0; kb < 4; ++kb) {
        __syncthreads();
#pragma unroll
        for (int j = 0; j < 4; ++j) {
            gld16(gA + kb * 64 + j * 32 * DEPTH, lA + j * 32 * 64);
            gld16(gB + kb * 64 + j * 32 * DEPTH, lB + j * 32 * 64);
        }
        __syncthreads();
#pragma unroll
        for (int ks = 0; ks < 2; ++ks) {
            const int ph = ((ks * 4 + quad) ^ (l15 & 7)) * 8;
            bf16x8 a[4], b[4];
#pragma unroll
            for (int fi = 0; fi < 4; ++fi)
                a[fi] = *reinterpret_cast<const bf16x8*>(As + (wy * 64 + fi * 16 + l15) * 64 + ph);
#pragma unroll
            for (int fj = 0; fj < 4; ++fj)
                b[fj] = *reinterpret_cast<const bf16x8*>(Bs + (wx * 64 + fj * 16 + l15) * 64 + ph);
#pragma unroll
            for (int fi = 0; fi < 4; ++fi)
#pragma unroll
                for (int fj = 0; fj < 4; ++fj)
                    acc[fi][fj] = __builtin_amdgcn_mfma_f32_16x16x32_bf16(a[fi], b[fj], acc[fi][fj], 0, 0, 0);
        }
    }

    // ---- register-side epilogue: per query (col), reduce its 64 in-wave codes ----
#pragma unroll
    for (int fj = 0; fj < 4; ++fj) {
        float m1 = 3.4e38f, m2 = 3.4e38f;
#pragma unroll
        for (int fi = 0; fi < 4; ++fi)
#pragma unroll
            for (int r = 0; r < 4; ++r) {
                float x = fmaf(-2.0f, acc[fi][fj][r], szq[fj]);
                m2 = fminf(m2, fmaxf(m1, x));
                m1 = fminf(m1, x);
            }
        // combine the 4 quad-lanes holding this query's other code rows: xor 16, 32
#pragma unroll
        for (int mm = 16; mm <= 32; mm <<= 1) {
            float o1 = __shfl_xor(m1, mm, 64);
            float o2 = __shfl_xor(m2, mm, 64);
            m2 = fminf(fminf(m2, o2), fmaxf(m1, o1));
            m1 = fminf(m1, o1);
        }
        // argmin: match-scan vs final m1 (pure VALU), then 2-round u32 min
        u32 kl = 0xFFFFFFFFu;
#pragma unroll
        for (int fi = 0; fi < 4; ++fi)
#pragma unroll
            for (int r = 0; r < 4; ++r) {
                float x = fmaf(-2.0f, acc[fi][fj][r], szq[fj]);
                u32 cd = (u32)(wy * 64 + fi * 16 + quad * 4 + r);
                kl = (x == m1 && cd < kl) ? cd : kl;
            }
#pragma unroll
        for (int mm = 16; mm <= 32; mm <<= 1) {
            u32 ok = __shfl_xor(kl, mm, 64);
            kl = kl < ok ? kl : ok;
        }
        if (quad == 0) {
            int q = wx * 64 + fj * 16 + l15;
            keyred[q * 2 + wy] = ((u64)__float_as_uint(m1) << 32) | kl;
            m2red[q * 2 + wy]  = m2;
        }
    }
    __syncthreads();
    if (t < 128) {
        int n = n0 + t;
        u64 ka = keyred[t * 2], kb2 = keyred[t * 2 + 1];
        u64 kmin = umin64(ka, kb2), kmax = umax64(ka, kb2);
        float m1 = __uint_as_float((u32)(kmin >> 32));
        float m2 = fminf(fminf(m2red[t * 2], m2red[t * 2 + 1]),
                         __uint_as_float((u32)(kmax >> 32)));
        float E = 0.008f * sqrtf(sz[n]) * sqrtf(__uint_as_float(*wmax2)) + 5.0e-5f;
        u32 low = (u32)kmin;                          // k1 local in [0,128)
        u32 flag = (m2 <= m1 + 2.0f * E) ? 0x80000000u : 0u;
        tilePack[(size_t)kt * NVEC + n] = ((u64)__float_as_uint(m1) << 32) | (u64)(low | flag);
    }
}

// exact fp32 refine (round-3 verbatim except kt-major tilePack indexing).
__global__ __launch_bounds__(256) void k_refine(const float* __restrict__ z,
                                                const float* __restrict__ W,
                                                const float* __restrict__ sz,
                                                const u32* __restrict__ wmax2,
                                                const u64* __restrict__ tp,
                                                u64* __restrict__ best) {
    __shared__ float zt[32][264];
    const int n0 = blockIdx.x * 32;
    const int b = n0 >> 10, hw0 = n0 & 1023;
    const int t = threadIdx.x;
    {
        int hw = t & 31, cg = t >> 5;
        const float* zb = z + (size_t)b * 262144 + hw0 + hw;
        for (int i = 0; i < 32; ++i) {
            int c = i * 8 + cg;
            zt[hw][c] = zb[(size_t)c * 1024];
        }
    }
    __syncthreads();
    const float wmaxv = sqrtf(__uint_as_float(*wmax2));
    const int w = t >> 6, lane = t & 63;
    for (int rr = w; rr < 32; rr += 4) {
        const int n = n0 + rr;
        u64 p0 = tp[(size_t)lane * NVEC + n];
        u64 p1 = tp[(size_t)(lane + 64) * NVEC + n];
        float f0 = __uint_as_float((u32)(p0 >> 32));
        float f1 = __uint_as_float((u32)(p1 >> 32));
        float g = fminf(f0, f1);
#pragma unroll
        for (int mm = 1; mm < 64; mm <<= 1) g = fminf(g, __shfl_xor(g, mm, 64));
        const float szv = sz[n];
        const float E = 0.008f * sqrtf(szv) * wmaxv + 5.0e-5f;
        const float tau = g + 2.0f * E;
        const float4* zrow = reinterpret_cast<const float4*>(&zt[rr][0]);
        u64 mykey = ~0ull;
#pragma unroll
        for (int half = 0; half < 2; ++half) {
            const u64 p = half ? p1 : p0;
            const float m1 = half ? f1 : f0;
            const u32 low = (u32)p;
            const bool qual = (m1 <= tau);
            const bool fl = (low & 0x80000000u) != 0u;
            if (qual && !fl) {
                u32 kg = (u32)((lane + half * 64) * 128) + (low & 0x7FFFFFFFu);
                const float4* wr = reinterpret_cast<const float4*>(W + (size_t)kg * DEPTH);
                float a = 0.0f;
                for (int c = 0; c < 64; ++c) {
                    float4 wv = wr[c]; float4 zv = zrow[c];
                    a = fmaf(zv.x, wv.x, a); a = fmaf(zv.y, wv.y, a);
                    a = fmaf(zv.z, wv.z, a); a = fmaf(zv.w, wv.w, a);
                }
                float dv = szv - 2.0f * a;
                mykey = umin64(mykey, ((u64)__float_as_uint(dv) << 32) | kg);
            }
            u64 bal = __ballot(qual && fl);
            while (bal) {
                int lt = __builtin_ctzll(bal);
                bal &= bal - 1;
                int ktile = lt + half * 64;
#pragma unroll
                for (int s = 0; s < 2; ++s) {
                    u32 kg = (u32)(ktile * 128 + s * 64 + lane);
                    const float4* wr = reinterpret_cast<const float4*>(W + (size_t)kg * DEPTH);
                    float a = 0.0f;
                    for (int c = 0; c < 64; ++c) {
                        float4 wv = wr[c]; float4 zv = zrow[c];
                        a = fmaf(zv.x, wv.x, a); a = fmaf(zv.y, wv.y, a);
                        a = fmaf(zv.z, wv.z, a); a = fmaf(zv.w, wv.w, a);
                    }
                    float dv = szv - 2.0f * a;
                    mykey = umin64(mykey, ((u64)__float_as_uint(dv) << 32) | kg);
                }
            }
        }
#pragma unroll
        for (int mm = 1; mm < 64; mm <<= 1)
            mykey = umin64(mykey, __shfl_xor(mykey, mm, 64));
        if (lane == 0) best[n] = mykey;
    }
}

// gather W[idx] -> z_q in [B,C,H,W] layout, idx as floats, loss partials (round-1 verbatim).
__global__ __launch_bounds__(256) void k_epilogue(const float* __restrict__ z,
                                                  const float* __restrict__ Wc,
                                                  const u64* __restrict__ best,
                                                  float* __restrict__ out,
                                                  float* __restrict__ lossacc) {
    __shared__ unsigned kk[64];
    __shared__ float red[256];
    int bid = blockIdx.x;
    int b = bid >> 4, hw0 = (bid & 15) << 6;
    int n0 = bid << 6;
    int t = threadIdx.x, r = t & 63, cg = t >> 6;
    if (t < 64) {
        unsigned ki = (unsigned)(best[n0 + t] & 0xffffffffull);
        kk[t] = ki;
        out[IDX_OFF + n0 + t] = (float)ki;
    }
    __syncthreads();
    const float* wrow = Wc + (size_t)kk[r] * DEPTH;
    int zbase = b * 262144 + hw0 + r;
    float part = 0.0f;
    for (int c = cg; c < DEPTH; c += 4) {
        float wv = wrow[c];
        float zv = z[zbase + c * 1024];
        out[zbase + c * 1024] = wv;
        float df = wv - zv;
        part = fmaf(df, df, part);
    }
    red[t] = part;
    __syncthreads();
    for (int s = 128; s > 0; s >>= 1) {
        if (t < s) red[t] += red[t + s];
        __syncthreads();
    }
    if (t == 0) atomicAdd(lossacc, red[0]);
}

__global__ void k_loss_final(float* __restrict__ out) {
    out[LOSS_OFF] = out[LOSS_OFF] * (1.25f / 4194304.0f);
}

extern "C" void kernel_launch(void* const* d_in, const int* in_sizes, int n_in,
                              void* d_out, int out_size, void* d_ws, size_t ws_size,
                              hipStream_t stream) {
    const float* z = (const float*)d_in[0];
    const float* W = (const float*)d_in[1];
    float* out = (float*)d_out;
    char* ws = (char*)d_ws;

    __bf16* Zh    = (__bf16*)ws;                         // 8,388,608 B
    __bf16* Wh    = (__bf16*)(ws + 8388608);             // 8,388,608 B
    float*  sz    = (float*) (ws + 16777216);            // 65,536 B
    u64*    best  = (u64*)   (ws + 16842752);            // 131,072 B
    u32*    wmax2 = (u32*)   (ws + 16973824);            // 4 B

    u64* tilePack = (u64*)out;                           // 16 MB in z_q region
    float* lossacc = out + LOSS_OFF;

    k_init      <<<dim3(1),         dim3(64),  0, stream>>>(wmax2, out);
    k_prep_w    <<<dim3(4096),      dim3(256), 0, stream>>>(W, Wh, wmax2);
    k_prep_z    <<<dim3(16, 4, 16), dim3(256), 0, stream>>>(z, Zh);
    k_rownorm   <<<dim3(256),       dim3(256), 0, stream>>>(z, sz);
    k_gemm      <<<dim3(128, 128),  dim3(256), 0, stream>>>(Wh, Zh, sz, wmax2, tilePack);
    k_refine    <<<dim3(512),       dim3(256), 0, stream>>>(z, W, sz, wmax2, tilePack, best);
    k_epilogue  <<<dim3(256),       dim3(256), 0, stream>>>(z, W, best, out, lossacc);
    k_loss_final<<<dim3(1),         dim3(1),   0, stream>>>(out);
}

// Round 5
// 395.261 us; speedup vs baseline: 13.2126x; 1.4494x over previous
//
#include <hip/hip_runtime.h>
#include <cstdint>

// VectorQuantizer on MI355X — round 5: remove the 16,384-way serialized atomicMax in
// k_prep_w (round-4 profile: 190 us at 0.7% VALUBusy = pure cross-XCD atomic stall).
// Per-row norms -> plain array (in d_out scratch), single-block max-reduce kernel.
// GEMM/refine/epilogue unchanged from round 4 (which hit its prediction).
//
// d_out (fp32 flat): z_q [16,256,32,32] (4194304) | loss (1) | idx (16384 as floats)
// z_q region doubles as scratch: wnorm2 (64 KB, then dead) -> tilePack (16 MB) -> z_q.

using u64 = unsigned long long;
using u32 = unsigned int;

#define NVEC   16384
#define NEMB   16384
#define DEPTH  256
#define LOSS_OFF 4194304
#define IDX_OFF  4194305

typedef __bf16 bf16x8 __attribute__((ext_vector_type(8)));
typedef float  f32x4  __attribute__((ext_vector_type(4)));

__device__ __forceinline__ void gld16(const void* g, void* l) {
    __builtin_amdgcn_global_load_lds(
        (const __attribute__((address_space(1))) char*)g,
        (__attribute__((address_space(3))) char*)l, 16, 0, 0);
}
__device__ __forceinline__ u64 umin64(u64 a, u64 b) { return a < b ? a : b; }
__device__ __forceinline__ u64 umax64(u64 a, u64 b) { return a > b ? a : b; }

__global__ void k_init(float* __restrict__ out) {
    if (threadIdx.x == 0) out[LOSS_OFF] = 0.0f;
}

// W [16384][256] f32 -> Wh bf16 (RNE); per-row norm^2 -> wnorm2 (NO atomics).
__global__ __launch_bounds__(256) void k_prep_w(const float* __restrict__ W,
                                                __bf16* __restrict__ Wh,
                                                float* __restrict__ wnorm2) {
    int t = threadIdx.x, w = t >> 6, lane = t & 63;
    int row = blockIdx.x * 4 + w;
    const float4 v = *reinterpret_cast<const float4*>(W + (size_t)row * DEPTH + lane * 4);
    __bf16 h0 = (__bf16)v.x, h1 = (__bf16)v.y, h2 = (__bf16)v.z, h3 = (__bf16)v.w;
    ushort4 pk;
    pk.x = __builtin_bit_cast(unsigned short, h0);
    pk.y = __builtin_bit_cast(unsigned short, h1);
    pk.z = __builtin_bit_cast(unsigned short, h2);
    pk.w = __builtin_bit_cast(unsigned short, h3);
    *reinterpret_cast<ushort4*>(Wh + (size_t)row * DEPTH + lane * 4) = pk;
    float n2 = v.x * v.x + v.y * v.y + v.z * v.z + v.w * v.w;
#pragma unroll
    for (int s = 32; s > 0; s >>= 1) n2 += __shfl_down(n2, s, 64);
    if (lane == 0) wnorm2[row] = n2;
}

// single-block max-reduce of wnorm2[16384] -> *wmax2 (float bits in u32).
__global__ __launch_bounds__(256) void k_wmax(const float* __restrict__ wnorm2,
                                              u32* __restrict__ wmax2) {
    __shared__ float red[256];
    int t = threadIdx.x;
    float m = 0.0f;
    for (int i = t; i < NEMB; i += 256) m = fmaxf(m, wnorm2[i]);
    red[t] = m;
    __syncthreads();
    for (int s = 128; s > 0; s >>= 1) {
        if (t < s) red[t] = fmaxf(red[t], red[t + s]);
        __syncthreads();
    }
    if (t == 0) *wmax2 = __float_as_uint(red[0]);
}

// z [16][256][1024] f32 -> Zh [n=16384][c=256] bf16 (transpose + convert)
__global__ __launch_bounds__(256) void k_prep_z(const float* __restrict__ z, __bf16* __restrict__ Zh) {
    __shared__ float tile[64][65];
    int hw0 = blockIdx.x * 64, c0 = blockIdx.y * 64, b = blockIdx.z;
    int t = threadIdx.x, lane = t & 63, grp = t >> 6;
    const float* zb = z + (size_t)b * 262144;
    for (int cc = grp; cc < 64; cc += 4)
        tile[cc][lane] = zb[(size_t)(c0 + cc) * 1024 + hw0 + lane];
    __syncthreads();
    for (int hh = grp; hh < 64; hh += 4)
        Zh[(size_t)(b * 1024 + hw0 + hh) * DEPTH + c0 + lane] = (__bf16)tile[lane][hh];
}

// sz[n] — EXACT copy of round-1 computation (exactness anchor; do not change).
__global__ __launch_bounds__(256) void k_rownorm(const float* __restrict__ z, float* __restrict__ sz) {
    __shared__ float red[4][64];
    int bid = blockIdx.x;
    int b = bid >> 4, hw0 = (bid & 15) << 6;
    int t = threadIdx.x, r = t & 63, cg = t >> 6;
    const float* zp = z + b * 262144 + hw0 + r;
    float acc = 0.0f;
    for (int c = cg; c < DEPTH; c += 4) {
        float v = zp[c * 1024];
        acc = fmaf(v, v, acc);
    }
    red[cg][r] = acc;
    __syncthreads();
    if (t < 64)
        sz[bid * 64 + t] = (red[0][t] + red[1][t]) + (red[2][t] + red[3][t]);
}

// MFMA GEMM, C-tile = 128 codes (rows) x 128 queries (cols), BK=64, XOR-swizzled LDS.
// Register-side two-min/argmin epilogue (round 4, verbatim).
__global__ __launch_bounds__(256, 4) void k_gemm(const __bf16* __restrict__ Wh,
                                                 const __bf16* __restrict__ Zh,
                                                 const float* __restrict__ sz,
                                                 const u32* __restrict__ wmax2,
                                                 u64* __restrict__ tilePack) {
    __shared__ __bf16 As[128 * 64];
    __shared__ __bf16 Bs[128 * 64];
    __shared__ u64   keyred[128 * 2];
    __shared__ float m2red[128 * 2];
    const int kt = blockIdx.x, nt = blockIdx.y;
    const int k0 = kt * 128, n0 = nt * 128;
    const int t = threadIdx.x, w = t >> 6, lane = t & 63;
    const int quad = lane >> 4, l15 = lane & 15;
    const int wy = w >> 1, wx = w & 1;

    const int rowS = w * 8 + (lane >> 3);
    const int colb = (((lane & 7) ^ (lane >> 3)) * 8);
    const __bf16* gA = Wh + (size_t)(k0 + rowS) * DEPTH + colb;
    const __bf16* gB = Zh + (size_t)(n0 + rowS) * DEPTH + colb;
    __bf16* lA = As + w * 8 * 64;
    __bf16* lB = Bs + w * 8 * 64;

    f32x4 acc[4][4] = {};
    float szq[4];
#pragma unroll
    for (int fj = 0; fj < 4; ++fj)
        szq[fj] = sz[n0 + wx * 64 + fj * 16 + l15];

    for (int kb = 0; kb < 4; ++kb) {
        __syncthreads();
#pragma unroll
        for (int j = 0; j < 4; ++j) {
            gld16(gA + kb * 64 + j * 32 * DEPTH, lA + j * 32 * 64);
            gld16(gB + kb * 64 + j * 32 * DEPTH, lB + j * 32 * 64);
        }
        __syncthreads();
#pragma unroll
        for (int ks = 0; ks < 2; ++ks) {
            const int ph = ((ks * 4 + quad) ^ (l15 & 7)) * 8;
            bf16x8 a[4], b[4];
#pragma unroll
            for (int fi = 0; fi < 4; ++fi)
                a[fi] = *reinterpret_cast<const bf16x8*>(As + (wy * 64 + fi * 16 + l15) * 64 + ph);
#pragma unroll
            for (int fj = 0; fj < 4; ++fj)
                b[fj] = *reinterpret_cast<const bf16x8*>(Bs + (wx * 64 + fj * 16 + l15) * 64 + ph);
#pragma unroll
            for (int fi = 0; fi < 4; ++fi)
#pragma unroll
                for (int fj = 0; fj < 4; ++fj)
                    acc[fi][fj] = __builtin_amdgcn_mfma_f32_16x16x32_bf16(a[fi], b[fj], acc[fi][fj], 0, 0, 0);
        }
    }

#pragma unroll
    for (int fj = 0; fj < 4; ++fj) {
        float m1 = 3.4e38f, m2 = 3.4e38f;
#pragma unroll
        for (int fi = 0; fi < 4; ++fi)
#pragma unroll
            for (int r = 0; r < 4; ++r) {
                float x = fmaf(-2.0f, acc[fi][fj][r], szq[fj]);
                m2 = fminf(m2, fmaxf(m1, x));
                m1 = fminf(m1, x);
            }
#pragma unroll
        for (int mm = 16; mm <= 32; mm <<= 1) {
            float o1 = __shfl_xor(m1, mm, 64);
            float o2 = __shfl_xor(m2, mm, 64);
            m2 = fminf(fminf(m2, o2), fmaxf(m1, o1));
            m1 = fminf(m1, o1);
        }
        u32 kl = 0xFFFFFFFFu;
#pragma unroll
        for (int fi = 0; fi < 4; ++fi)
#pragma unroll
            for (int r = 0; r < 4; ++r) {
                float x = fmaf(-2.0f, acc[fi][fj][r], szq[fj]);
                u32 cd = (u32)(wy * 64 + fi * 16 + quad * 4 + r);
                kl = (x == m1 && cd < kl) ? cd : kl;
            }
#pragma unroll
        for (int mm = 16; mm <= 32; mm <<= 1) {
            u32 ok = __shfl_xor(kl, mm, 64);
            kl = kl < ok ? kl : ok;
        }
        if (quad == 0) {
            int q = wx * 64 + fj * 16 + l15;
            keyred[q * 2 + wy] = ((u64)__float_as_uint(m1) << 32) | kl;
            m2red[q * 2 + wy]  = m2;
        }
    }
    __syncthreads();
    if (t < 128) {
        int n = n0 + t;
        u64 ka = keyred[t * 2], kb2 = keyred[t * 2 + 1];
        u64 kmin = umin64(ka, kb2), kmax = umax64(ka, kb2);
        float m1 = __uint_as_float((u32)(kmin >> 32));
        float m2 = fminf(fminf(m2red[t * 2], m2red[t * 2 + 1]),
                         __uint_as_float((u32)(kmax >> 32)));
        float E = 0.008f * sqrtf(sz[n]) * sqrtf(__uint_as_float(*wmax2)) + 5.0e-5f;
        u32 low = (u32)kmin;
        u32 flag = (m2 <= m1 + 2.0f * E) ? 0x80000000u : 0u;
        tilePack[(size_t)kt * NVEC + n] = ((u64)__float_as_uint(m1) << 32) | (u64)(low | flag);
    }
}

// exact fp32 refine (round-4 verbatim).
__global__ __launch_bounds__(256) void k_refine(const float* __restrict__ z,
                                                const float* __restrict__ W,
                                                const float* __restrict__ sz,
                                                const u32* __restrict__ wmax2,
                                                const u64* __restrict__ tp,
                                                u64* __restrict__ best) {
    __shared__ float zt[32][264];
    const int n0 = blockIdx.x * 32;
    const int b = n0 >> 10, hw0 = n0 & 1023;
    const int t = threadIdx.x;
    {
        int hw = t & 31, cg = t >> 5;
        const float* zb = z + (size_t)b * 262144 + hw0 + hw;
        for (int i = 0; i < 32; ++i) {
            int c = i * 8 + cg;
            zt[hw][c] = zb[(size_t)c * 1024];
        }
    }
    __syncthreads();
    const float wmaxv = sqrtf(__uint_as_float(*wmax2));
    const int w = t >> 6, lane = t & 63;
    for (int rr = w; rr < 32; rr += 4) {
        const int n = n0 + rr;
        u64 p0 = tp[(size_t)lane * NVEC + n];
        u64 p1 = tp[(size_t)(lane + 64) * NVEC + n];
        float f0 = __uint_as_float((u32)(p0 >> 32));
        float f1 = __uint_as_float((u32)(p1 >> 32));
        float g = fminf(f0, f1);
#pragma unroll
        for (int mm = 1; mm < 64; mm <<= 1) g = fminf(g, __shfl_xor(g, mm, 64));
        const float szv = sz[n];
        const float E = 0.008f * sqrtf(szv) * wmaxv + 5.0e-5f;
        const float tau = g + 2.0f * E;
        const float4* zrow = reinterpret_cast<const float4*>(&zt[rr][0]);
        u64 mykey = ~0ull;
#pragma unroll
        for (int half = 0; half < 2; ++half) {
            const u64 p = half ? p1 : p0;
            const float m1 = half ? f1 : f0;
            const u32 low = (u32)p;
            const bool qual = (m1 <= tau);
            const bool fl = (low & 0x80000000u) != 0u;
            if (qual && !fl) {
                u32 kg = (u32)((lane + half * 64) * 128) + (low & 0x7FFFFFFFu);
                const float4* wr = reinterpret_cast<const float4*>(W + (size_t)kg * DEPTH);
                float a = 0.0f;
                for (int c = 0; c < 64; ++c) {
                    float4 wv = wr[c]; float4 zv = zrow[c];
                    a = fmaf(zv.x, wv.x, a); a = fmaf(zv.y, wv.y, a);
                    a = fmaf(zv.z, wv.z, a); a = fmaf(zv.w, wv.w, a);
                }
                float dv = szv - 2.0f * a;
                mykey = umin64(mykey, ((u64)__float_as_uint(dv) << 32) | kg);
            }
            u64 bal = __ballot(qual && fl);
            while (bal) {
                int lt = __builtin_ctzll(bal);
                bal &= bal - 1;
                int ktile = lt + half * 64;
#pragma unroll
                for (int s = 0; s < 2; ++s) {
                    u32 kg = (u32)(ktile * 128 + s * 64 + lane);
                    const float4* wr = reinterpret_cast<const float4*>(W + (size_t)kg * DEPTH);
                    float a = 0.0f;
                    for (int c = 0; c < 64; ++c) {
                        float4 wv = wr[c]; float4 zv = zrow[c];
                        a = fmaf(zv.x, wv.x, a); a = fmaf(zv.y, wv.y, a);
                        a = fmaf(zv.z, wv.z, a); a = fmaf(zv.w, wv.w, a);
                    }
                    float dv = szv - 2.0f * a;
                    mykey = umin64(mykey, ((u64)__float_as_uint(dv) << 32) | kg);
                }
            }
        }
#pragma unroll
        for (int mm = 1; mm < 64; mm <<= 1)
            mykey = umin64(mykey, __shfl_xor(mykey, mm, 64));
        if (lane == 0) best[n] = mykey;
    }
}

// gather W[idx] -> z_q in [B,C,H,W] layout, idx as floats, loss partials (round-1 verbatim).
__global__ __launch_bounds__(256) void k_epilogue(const float* __restrict__ z,
                                                  const float* __restrict__ Wc,
                                                  const u64* __restrict__ best,
                                                  float* __restrict__ out,
                                                  float* __restrict__ lossacc) {
    __shared__ unsigned kk[64];
    __shared__ float red[256];
    int bid = blockIdx.x;
    int b = bid >> 4, hw0 = (bid & 15) << 6;
    int n0 = bid << 6;
    int t = threadIdx.x, r = t & 63, cg = t >> 6;
    if (t < 64) {
        unsigned ki = (unsigned)(best[n0 + t] & 0xffffffffull);
        kk[t] = ki;
        out[IDX_OFF + n0 + t] = (float)ki;
    }
    __syncthreads();
    const float* wrow = Wc + (size_t)kk[r] * DEPTH;
    int zbase = b * 262144 + hw0 + r;
    float part = 0.0f;
    for (int c = cg; c < DEPTH; c += 4) {
        float wv = wrow[c];
        float zv = z[zbase + c * 1024];
        out[zbase + c * 1024] = wv;
        float df = wv - zv;
        part = fmaf(df, df, part);
    }
    red[t] = part;
    __syncthreads();
    for (int s = 128; s > 0; s >>= 1) {
        if (t < s) red[t] += red[t + s];
        __syncthreads();
    }
    if (t == 0) atomicAdd(lossacc, red[0]);
}

__global__ void k_loss_final(float* __restrict__ out) {
    out[LOSS_OFF] = out[LOSS_OFF] * (1.25f / 4194304.0f);
}

extern "C" void kernel_launch(void* const* d_in, const int* in_sizes, int n_in,
                              void* d_out, int out_size, void* d_ws, size_t ws_size,
                              hipStream_t stream) {
    const float* z = (const float*)d_in[0];
    const float* W = (const float*)d_in[1];
    float* out = (float*)d_out;
    char* ws = (char*)d_ws;

    __bf16* Zh    = (__bf16*)ws;                         // 8,388,608 B
    __bf16* Wh    = (__bf16*)(ws + 8388608);             // 8,388,608 B
    float*  sz    = (float*) (ws + 16777216);            // 65,536 B
    u64*    best  = (u64*)   (ws + 16842752);            // 131,072 B
    u32*    wmax2 = (u32*)   (ws + 16973824);            // 4 B

    // d_out scratch staging: wnorm2 (first 64 KB, consumed by k_wmax before k_gemm
    // overwrites the whole region with tilePack), then tilePack (16 MB).
    float* wnorm2   = out;
    u64*   tilePack = (u64*)out;
    float* lossacc  = out + LOSS_OFF;

    k_init      <<<dim3(1),         dim3(64),  0, stream>>>(out);
    k_prep_w    <<<dim3(4096),      dim3(256), 0, stream>>>(W, Wh, wnorm2);
    k_wmax      <<<dim3(1),         dim3(256), 0, stream>>>(wnorm2, wmax2);
    k_prep_z    <<<dim3(16, 4, 16), dim3(256), 0, stream>>>(z, Zh);
    k_rownorm   <<<dim3(256),       dim3(256), 0, stream>>>(z, sz);
    k_gemm      <<<dim3(128, 128),  dim3(256), 0, stream>>>(Wh, Zh, sz, wmax2, tilePack);
    k_refine    <<<dim3(512),       dim3(256), 0, stream>>>(z, W, sz, wmax2, tilePack, best);
    k_epilogue  <<<dim3(256),       dim3(256), 0, stream>>>(z, W, best, out, lossacc);
    k_loss_final<<<dim3(1),         dim3(1),   0, stream>>>(out);
}